// Round 4
// baseline (783.275 us; speedup 1.0000x reference)
//
#include <hip/hip_runtime.h>

typedef unsigned short ushort_t;
typedef __attribute__((ext_vector_type(8))) _Float16 f16x8;
typedef __attribute__((ext_vector_type(4))) float f32x4;
typedef __attribute__((ext_vector_type(2))) unsigned long long u64x2;

#define ROWB 576   // 288 cols fp16 = 576B; swizzle XOR (bits 4-6) applied only to first 512B
#define MROWS 128  // rows per block

__device__ __forceinline__ ushort_t f2h(float x){ _Float16 h=(_Float16)x; return __builtin_bit_cast(ushort_t,h); }
__device__ __forceinline__ float h2f(ushort_t u){ return (float)__builtin_bit_cast(_Float16,u); }

// physical position of logical channel c within its 32-channel block:
// slot group g = (c%16)/4 holds logical k = {4g..4g+3, 16+4g..16+4g+3} contiguously (16B)
__device__ __forceinline__ int permc(int c){
    return (c & ~31) + (((c >> 2) & 3) << 3) + (c & 3) + (((c >> 4) & 1) << 2);
}

// ---------------- conv 3x3, 3->256, SAME ----------------
__global__ __launch_bounds__(256) void conv_k(const float* __restrict__ inp,
        const float* __restrict__ w, const float* __restrict__ bias,
        ushort_t* __restrict__ feat)
{
    __shared__ float sw_[6912];
    __shared__ float patch[27];
    int t = threadIdx.x;
    int b = blockIdx.x >> 12, p = blockIdx.x & 4095;
    int y = p >> 6, x = p & 63;
    for (int i = t; i < 6912; i += 256) sw_[i] = w[i];
    if (t < 27){
        int ci = t/9, r = t%9, dy = r/3, dx = r%3;
        int yy = y+dy-1, xx = x+dx-1;
        patch[t] = (yy>=0 && yy<64 && xx>=0 && xx<64) ? inp[((b*3+ci)<<12)+(yy<<6)+xx] : 0.f;
    }
    __syncthreads();
    float acc = bias[t];
    #pragma unroll
    for (int j = 0; j < 27; ++j) acc += patch[j]*sw_[t*27+j];
    // store channel-last, channel-permuted for fragment-friendly A reads
    feat[(((b<<12)+p)<<8) + permc(t)] = f2h(acc);
}

// ---------------- pack weights into MFMA fragment order (fp16) ----------------
// layout: [layer][kc][ntile(16)][lane(64)][8], layer0: kc 0..8 (k 256..259 = extra dims, rest 0)
__global__ __launch_bounds__(256) void pack_k(const float* __restrict__ w_in,
        const float* __restrict__ w_hid, ushort_t* __restrict__ packW)
{
    int i = blockIdx.x*256 + threadIdx.x;
    if (i >= 270336) return;
    int layer, rem;
    if (i < 73728){ layer = 0; rem = i; }
    else { int j = i - 73728; layer = 1 + (j >> 16); rem = j & 65535; }
    int j8 = rem & 7, frag = rem >> 3;
    int lane = frag & 63, kt = frag >> 6;
    int kc = kt >> 4, nt = kt & 15;
    int k = kc*32 + ((lane>>4)<<2) + (j8 & 3) + ((j8 >> 2) << 4);
    int n = (nt<<4) + (lane & 15);
    float val;
    if (layer == 0) val = (k < 260) ? w_in[k*256 + n] : 0.f;
    else            val = w_hid[((layer-1)*256 + k)*256 + n];
    packW[i] = f2h(val);
}

// ---------------- fused MLP layer: acts[128][K] (LDS) @ W -> relu -> acts ----------------
// Each wave owns 64 output cols and all 128 rows: per kc, 8 A-frags + 4 B-frags -> 32 MFMAs.
// Weight fragments for kc+1 prefetched into registers before the kc MFMA burst.
template<int KC>
__device__ __forceinline__ void mlp_layer(const ushort_t* __restrict__ wfrag,
        const float* __restrict__ bias, char* smem, int lane, int wave)
{
    const int l15 = lane & 15, g = lane >> 4;
    f32x4 acc[8][4];
    #pragma unroll
    for (int nt = 0; nt < 4; ++nt){
        float bv = bias[wave*64 + nt*16 + l15];
        #pragma unroll
        for (int mt = 0; mt < 8; ++mt)
            acc[mt][nt] = (f32x4){bv, bv, bv, bv};
    }
    const ushort_t* wbase = wfrag + (wave*256 + lane)*8;
    f16x8 bf[4], bfn[4];
    #pragma unroll
    for (int nt = 0; nt < 4; ++nt) bf[nt] = *(const f16x8*)(wbase + nt*512);
    #pragma unroll
    for (int kc = 0; kc < KC; ++kc){
        f16x8 af[8];
        #pragma unroll
        for (int mt = 0; mt < 8; ++mt){
            int m = mt*16 + l15;
            const char* row = smem + m*ROWB;
            int off = kc*64 + g*16;
            int o2 = (off < 512) ? (off ^ ((m & 7) << 4)) : off;  // extras region unswizzled
            af[mt] = *(const f16x8*)(row + o2);
        }
        if (kc + 1 < KC){
            const ushort_t* wp = wbase + (kc + 1)*8192;
            #pragma unroll
            for (int nt = 0; nt < 4; ++nt) bfn[nt] = *(const f16x8*)(wp + nt*512);
        }
        #pragma unroll
        for (int mt = 0; mt < 8; ++mt)
            #pragma unroll
            for (int nt = 0; nt < 4; ++nt)
                acc[mt][nt] = __builtin_amdgcn_mfma_f32_16x16x32_f16(af[mt], bf[nt], acc[mt][nt], 0, 0, 0);
        #pragma unroll
        for (int nt = 0; nt < 4; ++nt) bf[nt] = bfn[nt];
    }
    __syncthreads();   // all reads of current acts done
    #pragma unroll
    for (int mt = 0; mt < 8; ++mt){
        #pragma unroll
        for (int r = 0; r < 4; ++r){
            int m = mt*16 + g*4 + r;
            char* row = smem + m*ROWB;
            int sw = (m & 7) << 4;
            #pragma unroll
            for (int nt = 0; nt < 4; ++nt){
                float val = acc[mt][nt][r];
                val = val > 0.f ? val : 0.f;
                int n = wave*64 + nt*16 + l15;
                *(ushort_t*)(row + ((permc(n)*2) ^ sw)) = f2h(val);
            }
        }
    }
    __syncthreads();
}

// ---------------- main fused kernel: gather + 4 MFMA layers + out layer ----------------
__global__ __launch_bounds__(256, 2) void liif_k(
        const float* __restrict__ coord, const float* __restrict__ cell,
        const float* __restrict__ b_in, const float* __restrict__ b_hid,
        const float* __restrict__ w_out, const float* __restrict__ b_out,
        const ushort_t* __restrict__ feat, const ushort_t* __restrict__ packW,
        float2* __restrict__ preds, float* __restrict__ areas)
{
    __shared__ __align__(16) char smem[MROWS*ROWB];   // 73728 B
    const int t = threadIdx.x, lane = t & 63, wave = t >> 6;
    const int bi = blockIdx.x, v = bi & 3;
    const int tile = bi >> 2;              // [0,1024)
    const int b = tile >> 9;               // [0,2)
    const int rem = tile & 511;
    const int th = rem >> 5, tw = rem & 31;  // 16x8-pixel tiles: th [0,16), tw [0,32)

    // --- setup: gather feature rows + extras + area (2 threads per row, 256B each) ---
    {
        int m = t >> 1, q = t & 1;
        int qh = th*16 + (m >> 3), qw = tw*8 + (m & 7);
        int cidx = (((b<<8) + qh)<<8) + qw;
        float c0 = coord[cidx*2], c1 = coord[cidx*2 + 1];
        float ch = c0 + ((v & 2) ? 0.015625f : -0.015625f); ch = ch + 1e-6f;
        ch = fminf(fmaxf(ch, -1.f + 1e-6f), 1.f - 1e-6f);
        float cw = c1 + ((v & 1) ? 0.015625f : -0.015625f); cw = cw + 1e-6f;
        cw = fminf(fmaxf(cw, -1.f + 1e-6f), 1.f - 1e-6f);
        int ih = (int)floorf((ch + 1.f)*64.f*0.5f); ih = ih < 0 ? 0 : (ih > 63 ? 63 : ih);
        int iw = (int)floorf((cw + 1.f)*64.f*0.5f); iw = iw < 0 ? 0 : (iw > 63 ? 63 : iw);
        char* drow = smem + m*ROWB;
        int sw = (m & 7) << 4;
        const u64x2* src = (const u64x2*)(feat + ((((b<<6) + ih)<<6) + iw)*256 + q*128);
        #pragma unroll
        for (int c = 0; c < 16; ++c)
            *(u64x2*)(drow + ((q*256 + c*16) ^ sw)) = src[c];
        if (q == 0){
            float qch = (2.f*(float)ih + 1.f)*(1.f/64.f) - 1.f;
            float qcw = (2.f*(float)iw + 1.f)*(1.f/64.f) - 1.f;
            float relh = (c0 - qch)*64.f, relw = (c1 - qcw)*64.f;
            float rch = cell[b*2]*64.f, rcw = cell[b*2 + 1]*64.f;
            unsigned long long ex = (unsigned long long)f2h(relh)
                | ((unsigned long long)f2h(relw) << 16)
                | ((unsigned long long)f2h(rch)  << 32)
                | ((unsigned long long)f2h(rcw)  << 48);
            u64x2 e; e[0] = ex; e[1] = 0;
            u64x2 z; z[0] = 0;  z[1] = 0;
            // extras region [512,576) is NOT swizzled
            *(u64x2*)(drow + 512) = e;
            *(u64x2*)(drow + 528) = z;
            *(u64x2*)(drow + 544) = z;
            *(u64x2*)(drow + 560) = z;
            areas[((v*2 + b)<<16) + (qh<<8) + qw] = fabsf(relh*relw) + 1e-9f;
        }
    }
    __syncthreads();

    // --- 4 MFMA layers ---
    mlp_layer<9>(packW,                  b_in,        smem, lane, wave);
    mlp_layer<8>(packW + 73728,          b_hid,       smem, lane, wave);
    mlp_layer<8>(packW + 73728 + 65536,  b_hid + 256, smem, lane, wave);
    mlp_layer<8>(packW + 73728 + 131072, b_hid + 512, smem, lane, wave);

    // --- out layer 256->2 (fp32 VALU, 2 threads per row, 128 channels each) ---
    {
        int m = t >> 1, q = t & 1;
        char* drow = smem + m*ROWB;
        int sw = (m & 7) << 4;
        const float2* wo = (const float2*)w_out;
        float s0 = 0.f, s1 = 0.f;
        #pragma unroll
        for (int c = 0; c < 16; ++c){
            int o = q*256 + c*16;
            u64x2 chk = *(const u64x2*)(drow + (o ^ sw));
            int kblock = o >> 6, gg = (o >> 4) & 3;
            #pragma unroll
            for (int half = 0; half < 2; ++half){
                unsigned long long u = chk[half];
                #pragma unroll
                for (int jj = 0; jj < 4; ++jj){
                    int je = half*4 + jj;
                    int k = kblock*32 + 4*gg + (je & 3) + ((je >> 2) << 4);
                    float a = h2f((ushort_t)(u >> (16*jj)));
                    float2 wv = wo[k];
                    s0 += a*wv.x; s1 += a*wv.y;
                }
            }
        }
        s0 += __shfl_xor(s0, 1);
        s1 += __shfl_xor(s1, 1);
        if (q == 0){
            int qh = th*16 + (m >> 3), qw = tw*8 + (m & 7);
            float2 pr; pr.x = s0 + b_out[0]; pr.y = s1 + b_out[1];
            preds[((v*2 + b)<<16) + (qh<<8) + qw] = pr;
        }
    }
}

// ---------------- ensemble combine + softmax ----------------
__global__ __launch_bounds__(256) void comb_k(const float2* __restrict__ preds,
        const float* __restrict__ areas, float* __restrict__ out)
{
    int idx = blockIdx.x*256 + threadIdx.x;   // 131072
    int b = idx >> 16, pix = idx & 65535;
    float a[4]; float2 p[4];
    #pragma unroll
    for (int v = 0; v < 4; ++v){
        int base = ((v*2 + b)<<16) + pix;
        a[v] = areas[base]; p[v] = preds[base];
    }
    float tot = a[0] + a[1] + a[2] + a[3];
    float w0 = a[3]/tot, w1 = a[2]/tot, w2 = a[1]/tot, w3 = a[0]/tot;
    float r0 = p[0].x*w0 + p[1].x*w1 + p[2].x*w2 + p[3].x*w3;
    float r1 = p[0].y*w0 + p[1].y*w1 + p[2].y*w2 + p[3].y*w3;
    float mx = fmaxf(r0, r1);
    float e0 = expf(r0 - mx), e1 = expf(r1 - mx);
    float inv = 1.f/(e0 + e1);
    out[(b<<17) + pix]         = e0*inv;
    out[(b<<17) + 65536 + pix] = e1*inv;
}

extern "C" void kernel_launch(void* const* d_in, const int* in_sizes, int n_in,
                              void* d_out, int out_size, void* d_ws, size_t ws_size,
                              hipStream_t stream)
{
    const float* inp   = (const float*)d_in[0];
    const float* coord = (const float*)d_in[1];
    const float* cell  = (const float*)d_in[2];
    const float* convw = (const float*)d_in[3];
    const float* convb = (const float*)d_in[4];
    const float* w_in  = (const float*)d_in[5];
    const float* b_in  = (const float*)d_in[6];
    const float* w_hid = (const float*)d_in[7];
    const float* b_hid = (const float*)d_in[8];
    const float* w_out = (const float*)d_in[9];
    const float* b_out = (const float*)d_in[10];
    (void)in_sizes; (void)n_in; (void)out_size; (void)ws_size;

    char* ws = (char*)d_ws;
    ushort_t* feat  = (ushort_t*)ws;                                  // 4,194,304 B
    ushort_t* packW = (ushort_t*)(ws + 4194304);                      //   540,672 B
    float2*   preds = (float2*)(ws + 4194304 + 540672);               // 4,194,304 B
    float*    areas = (float*)(ws + 4194304 + 540672 + 4194304);      // 2,097,152 B
    float* out = (float*)d_out;

    pack_k<<<dim3(1056), dim3(256), 0, stream>>>(w_in, w_hid, packW);
    conv_k<<<dim3(8192), dim3(256), 0, stream>>>(inp, convw, convb, feat);
    liif_k<<<dim3(4096), dim3(256), 0, stream>>>(coord, cell, b_in, b_hid,
                                                 w_out, b_out, feat, packW, preds, areas);
    comb_k<<<dim3(512), dim3(256), 0, stream>>>(preds, areas, out);
}

// Round 6
// 444.450 us; speedup vs baseline: 1.7623x; 1.7623x over previous
//
#include <hip/hip_runtime.h>

typedef unsigned short ushort_t;
typedef __attribute__((ext_vector_type(8))) _Float16 f16x8;
typedef __attribute__((ext_vector_type(4))) float f32x4;
typedef __attribute__((ext_vector_type(2))) unsigned long long u64x2;

#define ROWB 576   // 288 cols fp16 = 576B; swizzle XOR (bits 4-6) applied only to first 512B

__device__ __forceinline__ ushort_t f2h(float x){ _Float16 h=(_Float16)x; return __builtin_bit_cast(ushort_t,h); }
__device__ __forceinline__ float h2f(ushort_t u){ return (float)__builtin_bit_cast(_Float16,u); }

// physical position of logical channel c within its 32-channel block:
// slot group g = (c%16)/4 holds logical k = {4g..4g+3, 16+4g..16+4g+3} contiguously (16B)
__device__ __forceinline__ int permc(int c){
    return (c & ~31) + (((c >> 2) & 3) << 3) + (c & 3) + (((c >> 4) & 1) << 2);
}

// ---------------- conv 3x3, 3->256, SAME ----------------
__global__ __launch_bounds__(256) void conv_k(const float* __restrict__ inp,
        const float* __restrict__ w, const float* __restrict__ bias,
        ushort_t* __restrict__ feat)
{
    __shared__ float sw_[6912];
    __shared__ float patch[27];
    int t = threadIdx.x;
    int b = blockIdx.x >> 12, p = blockIdx.x & 4095;
    int y = p >> 6, x = p & 63;
    for (int i = t; i < 6912; i += 256) sw_[i] = w[i];
    if (t < 27){
        int ci = t/9, r = t%9, dy = r/3, dx = r%3;
        int yy = y+dy-1, xx = x+dx-1;
        patch[t] = (yy>=0 && yy<64 && xx>=0 && xx<64) ? inp[((b*3+ci)<<12)+(yy<<6)+xx] : 0.f;
    }
    __syncthreads();
    float acc = bias[t];
    #pragma unroll
    for (int j = 0; j < 27; ++j) acc += patch[j]*sw_[t*27+j];
    // store channel-last, channel-permuted for fragment-friendly A reads
    feat[(((b<<12)+p)<<8) + permc(t)] = f2h(acc);
}

// ---------------- pack weights into MFMA fragment order (fp16) ----------------
// layout: [layer][kc][ntile(16)][lane(64)][8], layer0: kc 0..8 (k 256..259 = extra dims, rest 0)
__global__ __launch_bounds__(256) void pack_k(const float* __restrict__ w_in,
        const float* __restrict__ w_hid, ushort_t* __restrict__ packW)
{
    int i = blockIdx.x*256 + threadIdx.x;
    if (i >= 270336) return;
    int layer, rem;
    if (i < 73728){ layer = 0; rem = i; }
    else { int j = i - 73728; layer = 1 + (j >> 16); rem = j & 65535; }
    int j8 = rem & 7, frag = rem >> 3;
    int lane = frag & 63, kt = frag >> 6;
    int kc = kt >> 4, nt = kt & 15;
    int k = kc*32 + ((lane>>4)<<2) + (j8 & 3) + ((j8 >> 2) << 4);
    int n = (nt<<4) + (lane & 15);
    float val;
    if (layer == 0) val = (k < 260) ? w_in[k*256 + n] : 0.f;
    else            val = w_hid[((layer-1)*256 + k)*256 + n];
    packW[i] = f2h(val);
}

// ---------------- fused MLP layer: acts[64][K] (LDS) @ W -> relu -> acts ----------------
// 8 waves; wave owns all 64 rows x 32 cols (ntiles wave*2, wave*2+1).
// Per kc: 4 A-frags (LDS) + 2 B-frags (L2, depth-1 prefetched) -> 8 MFMAs. acc = 32 regs.
template<int KC>
__device__ __forceinline__ void mlp_layer(const ushort_t* __restrict__ wfrag,
        const float* __restrict__ bias, char* smem, int lane, int wave)
{
    const int l15 = lane & 15, g = lane >> 4;
    f32x4 acc[4][2];
    #pragma unroll
    for (int nt = 0; nt < 2; ++nt){
        float bv = bias[wave*32 + nt*16 + l15];
        #pragma unroll
        for (int mt = 0; mt < 4; ++mt)
            acc[mt][nt] = (f32x4){bv, bv, bv, bv};
    }
    const ushort_t* wbase = wfrag + (wave*2*64 + lane)*8;
    f16x8 bf[2], bfn[2];
    #pragma unroll
    for (int nt = 0; nt < 2; ++nt) bf[nt] = *(const f16x8*)(wbase + nt*512);
    #pragma unroll
    for (int kc = 0; kc < KC; ++kc){
        f16x8 af[4];
        #pragma unroll
        for (int mt = 0; mt < 4; ++mt){
            int m = mt*16 + l15;
            const char* row = smem + m*ROWB;
            int off = kc*64 + g*16;
            int o2 = (off < 512) ? (off ^ ((m & 7) << 4)) : off;  // extras region unswizzled
            af[mt] = *(const f16x8*)(row + o2);
        }
        if (kc + 1 < KC){
            const ushort_t* wp = wbase + (kc + 1)*8192;
            #pragma unroll
            for (int nt = 0; nt < 2; ++nt) bfn[nt] = *(const f16x8*)(wp + nt*512);
        }
        #pragma unroll
        for (int mt = 0; mt < 4; ++mt)
            #pragma unroll
            for (int nt = 0; nt < 2; ++nt)
                acc[mt][nt] = __builtin_amdgcn_mfma_f32_16x16x32_f16(af[mt], bf[nt], acc[mt][nt], 0, 0, 0);
        #pragma unroll
        for (int nt = 0; nt < 2; ++nt) bf[nt] = bfn[nt];
    }
    __syncthreads();   // all reads of current acts done
    #pragma unroll
    for (int mt = 0; mt < 4; ++mt){
        #pragma unroll
        for (int r = 0; r < 4; ++r){
            int m = mt*16 + g*4 + r;
            char* row = smem + m*ROWB;
            int sw = (m & 7) << 4;
            #pragma unroll
            for (int nt = 0; nt < 2; ++nt){
                float val = acc[mt][nt][r];
                val = val > 0.f ? val : 0.f;
                int n = wave*32 + nt*16 + l15;
                *(ushort_t*)(row + ((permc(n)*2) ^ sw)) = f2h(val);
            }
        }
    }
    __syncthreads();
}

// ---------------- main fused kernel: gather + 4 MFMA layers + out layer ----------------
__global__ __launch_bounds__(512, 4) void liif_k(
        const float* __restrict__ coord, const float* __restrict__ cell,
        const float* __restrict__ b_in, const float* __restrict__ b_hid,
        const float* __restrict__ w_out, const float* __restrict__ b_out,
        const ushort_t* __restrict__ feat, const ushort_t* __restrict__ packW,
        float2* __restrict__ preds, float* __restrict__ areas)
{
    __shared__ __align__(16) char smem[64*ROWB];   // 36864 B
    const int t = threadIdx.x, lane = t & 63, wave = t >> 6;   // wave in [0,8)
    const int bi = blockIdx.x, v = bi & 3;
    const int tile = bi >> 2;
    const int b = tile >> 10, th = (tile >> 5) & 31, tw = tile & 31;

    // --- setup: gather feature rows + extras + area (8 threads per row, 64B each) ---
    {
        int m = t >> 3, q = t & 7;
        int qh = th*8 + (m >> 3), qw = tw*8 + (m & 7);
        int cidx = (((b<<8) + qh)<<8) + qw;
        float c0 = coord[cidx*2], c1 = coord[cidx*2 + 1];
        float ch = c0 + ((v & 2) ? 0.015625f : -0.015625f); ch = ch + 1e-6f;
        ch = fminf(fmaxf(ch, -1.f + 1e-6f), 1.f - 1e-6f);
        float cw = c1 + ((v & 1) ? 0.015625f : -0.015625f); cw = cw + 1e-6f;
        cw = fminf(fmaxf(cw, -1.f + 1e-6f), 1.f - 1e-6f);
        int ih = (int)floorf((ch + 1.f)*64.f*0.5f); ih = ih < 0 ? 0 : (ih > 63 ? 63 : ih);
        int iw = (int)floorf((cw + 1.f)*64.f*0.5f); iw = iw < 0 ? 0 : (iw > 63 ? 63 : iw);
        char* drow = smem + m*ROWB;
        int sw = (m & 7) << 4;
        const u64x2* src = (const u64x2*)(feat + ((((b<<6) + ih)<<6) + iw)*256 + q*32);
        #pragma unroll
        for (int c = 0; c < 4; ++c)
            *(u64x2*)(drow + ((q*64 + c*16) ^ sw)) = src[c];
        if (q == 0){
            float qch = (2.f*(float)ih + 1.f)*(1.f/64.f) - 1.f;
            float qcw = (2.f*(float)iw + 1.f)*(1.f/64.f) - 1.f;
            float relh = (c0 - qch)*64.f, relw = (c1 - qcw)*64.f;
            float rch = cell[b*2]*64.f, rcw = cell[b*2 + 1]*64.f;
            unsigned long long ex = (unsigned long long)f2h(relh)
                | ((unsigned long long)f2h(relw) << 16)
                | ((unsigned long long)f2h(rch)  << 32)
                | ((unsigned long long)f2h(rcw)  << 48);
            u64x2 e; e[0] = ex; e[1] = 0;
            u64x2 z; z[0] = 0;  z[1] = 0;
            // extras region [512,576) is NOT swizzled
            *(u64x2*)(drow + 512) = e;
            *(u64x2*)(drow + 528) = z;
            *(u64x2*)(drow + 544) = z;
            *(u64x2*)(drow + 560) = z;
            areas[((v*2 + b)<<16) + (qh<<8) + qw] = fabsf(relh*relw) + 1e-9f;
        }
    }
    __syncthreads();

    // --- 4 MFMA layers ---
    mlp_layer<9>(packW,                  b_in,        smem, lane, wave);
    mlp_layer<8>(packW + 73728,          b_hid,       smem, lane, wave);
    mlp_layer<8>(packW + 73728 + 65536,  b_hid + 256, smem, lane, wave);
    mlp_layer<8>(packW + 73728 + 131072, b_hid + 512, smem, lane, wave);

    // --- out layer 256->2 (fp32 VALU, 8 threads per row, 64 channels each) ---
    {
        int m = t >> 3, q = t & 7;
        char* drow = smem + m*ROWB;
        int sw = (m & 7) << 4;
        const float2* wo = (const float2*)w_out;
        float s0 = 0.f, s1 = 0.f;
        #pragma unroll
        for (int c = 0; c < 4; ++c){
            int o = q*64 + c*16;
            u64x2 chk = *(const u64x2*)(drow + (o ^ sw));
            int kblock = o >> 6, gg = (o >> 4) & 3;
            #pragma unroll
            for (int half = 0; half < 2; ++half){
                unsigned long long u = chk[half];
                #pragma unroll
                for (int jj = 0; jj < 4; ++jj){
                    int je = half*4 + jj;
                    int k = kblock*32 + 4*gg + (je & 3) + ((je >> 2) << 4);
                    float a = h2f((ushort_t)(u >> (16*jj)));
                    float2 wv = wo[k];
                    s0 += a*wv.x; s1 += a*wv.y;
                }
            }
        }
        s0 += __shfl_xor(s0, 1); s0 += __shfl_xor(s0, 2); s0 += __shfl_xor(s0, 4);
        s1 += __shfl_xor(s1, 1); s1 += __shfl_xor(s1, 2); s1 += __shfl_xor(s1, 4);
        if (q == 0){
            int qh = th*8 + (m >> 3), qw = tw*8 + (m & 7);
            float2 pr; pr.x = s0 + b_out[0]; pr.y = s1 + b_out[1];
            preds[((v*2 + b)<<16) + (qh<<8) + qw] = pr;
        }
    }
}

// ---------------- ensemble combine + softmax ----------------
__global__ __launch_bounds__(256) void comb_k(const float2* __restrict__ preds,
        const float* __restrict__ areas, float* __restrict__ out)
{
    int idx = blockIdx.x*256 + threadIdx.x;   // 131072
    int b = idx >> 16, pix = idx & 65535;
    float a[4]; float2 p[4];
    #pragma unroll
    for (int v = 0; v < 4; ++v){
        int base = ((v*2 + b)<<16) + pix;
        a[v] = areas[base]; p[v] = preds[base];
    }
    float tot = a[0] + a[1] + a[2] + a[3];
    float w0 = a[3]/tot, w1 = a[2]/tot, w2 = a[1]/tot, w3 = a[0]/tot;
    float r0 = p[0].x*w0 + p[1].x*w1 + p[2].x*w2 + p[3].x*w3;
    float r1 = p[0].y*w0 + p[1].y*w1 + p[2].y*w2 + p[3].y*w3;
    float mx = fmaxf(r0, r1);
    float e0 = expf(r0 - mx), e1 = expf(r1 - mx);
    float inv = 1.f/(e0 + e1);
    out[(b<<17) + pix]         = e0*inv;
    out[(b<<17) + 65536 + pix] = e1*inv;
}

extern "C" void kernel_launch(void* const* d_in, const int* in_sizes, int n_in,
                              void* d_out, int out_size, void* d_ws, size_t ws_size,
                              hipStream_t stream)
{
    const float* inp   = (const float*)d_in[0];
    const float* coord = (const float*)d_in[1];
    const float* cell  = (const float*)d_in[2];
    const float* convw = (const float*)d_in[3];
    const float* convb = (const float*)d_in[4];
    const float* w_in  = (const float*)d_in[5];
    const float* b_in  = (const float*)d_in[6];
    const float* w_hid = (const float*)d_in[7];
    const float* b_hid = (const float*)d_in[8];
    const float* w_out = (const float*)d_in[9];
    const float* b_out = (const float*)d_in[10];
    (void)in_sizes; (void)n_in; (void)out_size; (void)ws_size;

    char* ws = (char*)d_ws;
    ushort_t* feat  = (ushort_t*)ws;                                  // 4,194,304 B
    ushort_t* packW = (ushort_t*)(ws + 4194304);                      //   540,672 B
    float2*   preds = (float2*)(ws + 4194304 + 540672);               // 4,194,304 B
    float*    areas = (float*)(ws + 4194304 + 540672 + 4194304);      // 2,097,152 B
    float* out = (float*)d_out;

    pack_k<<<dim3(1056), dim3(256), 0, stream>>>(w_in, w_hid, packW);
    conv_k<<<dim3(8192), dim3(256), 0, stream>>>(inp, convw, convb, feat);
    liif_k<<<dim3(8192), dim3(512), 0, stream>>>(coord, cell, b_in, b_hid,
                                                 w_out, b_out, feat, packW, preds, areas);
    comb_k<<<dim3(512), dim3(256), 0, stream>>>(preds, areas, out);
}

// Round 7
// 424.335 us; speedup vs baseline: 1.8459x; 1.0474x over previous
//
#include <hip/hip_runtime.h>

typedef unsigned short ushort_t;
typedef __attribute__((ext_vector_type(8))) _Float16 f16x8;
typedef __attribute__((ext_vector_type(4))) float f32x4;
typedef __attribute__((ext_vector_type(2))) unsigned long long u64x2;

#define ROWB 576   // 288 cols fp16 = 576B; swizzle XOR bits 4-6 in [0,512), bits 4-5 in [512,576)

__device__ __forceinline__ ushort_t f2h(float x){ _Float16 h=(_Float16)x; return __builtin_bit_cast(ushort_t,h); }
__device__ __forceinline__ float h2f(ushort_t u){ return (float)__builtin_bit_cast(_Float16,u); }

// physical position of logical channel c within its 32-channel block:
// slot group g = (c%16)/4 holds logical k = {4g..4g+3, 16+4g..16+4g+3} contiguously (16B)
__device__ __forceinline__ int permc(int c){
    return (c & ~31) + (((c >> 2) & 3) << 3) + (c & 3) + (((c >> 4) & 1) << 2);
}

// ---------------- conv 3x3, 3->256, SAME ----------------
__global__ __launch_bounds__(256) void conv_k(const float* __restrict__ inp,
        const float* __restrict__ w, const float* __restrict__ bias,
        ushort_t* __restrict__ feat)
{
    __shared__ float sw_[6912];
    __shared__ float patch[27];
    int t = threadIdx.x;
    int b = blockIdx.x >> 12, p = blockIdx.x & 4095;
    int y = p >> 6, x = p & 63;
    for (int i = t; i < 6912; i += 256) sw_[i] = w[i];
    if (t < 27){
        int ci = t/9, r = t%9, dy = r/3, dx = r%3;
        int yy = y+dy-1, xx = x+dx-1;
        patch[t] = (yy>=0 && yy<64 && xx>=0 && xx<64) ? inp[((b*3+ci)<<12)+(yy<<6)+xx] : 0.f;
    }
    __syncthreads();
    float acc = bias[t];
    #pragma unroll
    for (int j = 0; j < 27; ++j) acc += patch[j]*sw_[t*27+j];
    feat[(((b<<12)+p)<<8) + permc(t)] = f2h(acc);
}

// ---------------- pack weights into MFMA fragment order (fp16) ----------------
// layout: [layer][kc][ntile(16)][lane(64)][8], layer0: kc 0..8 (k 256..259 = extra dims, rest 0)
__global__ __launch_bounds__(256) void pack_k(const float* __restrict__ w_in,
        const float* __restrict__ w_hid, ushort_t* __restrict__ packW)
{
    int i = blockIdx.x*256 + threadIdx.x;
    if (i >= 270336) return;
    int layer, rem;
    if (i < 73728){ layer = 0; rem = i; }
    else { int j = i - 73728; layer = 1 + (j >> 16); rem = j & 65535; }
    int j8 = rem & 7, frag = rem >> 3;
    int lane = frag & 63, kt = frag >> 6;
    int kc = kt >> 4, nt = kt & 15;
    int k = kc*32 + ((lane>>4)<<2) + (j8 & 3) + ((j8 >> 2) << 4);
    int n = (nt<<4) + (lane & 15);
    float val;
    if (layer == 0) val = (k < 260) ? w_in[k*256 + n] : 0.f;
    else            val = w_hid[((layer-1)*256 + k)*256 + n];
    packW[i] = f2h(val);
}

// ---------------- fused MLP layer, TRANSPOSED: Y^T = W^T (A) * X^T (B) ----------------
// 8 waves; wave owns 32 output channels (tiles wave*2, wave*2+1) for all 64 rows.
// Per kc: 4 B-act ds_reads (all rows) + 2 A-weight global loads -> 8 MFMAs; both depth-1 prefetched.
// D: lane holds col m=l15 (pixel row), rows n = NT*16 + 4g + reg -> clean b64 store at the
// permc position the next layer's B-read expects. acc = 32 regs.
template<int KC>
__device__ __forceinline__ void mlp_layer(const ushort_t* __restrict__ wfrag,
        const float* __restrict__ bias, char* smem, int lane, int wave)
{
    const int l15 = lane & 15, g = lane >> 4;
    const int swz  = (l15 & 7) << 4;
    const int swz2 = (l15 & 3) << 4;
    f32x4 acc[4][2];
    #pragma unroll
    for (int nt = 0; nt < 2; ++nt){
        f32x4 bv = *(const f32x4*)(bias + (wave*2 + nt)*16 + 4*g);
        #pragma unroll
        for (int mg = 0; mg < 4; ++mg) acc[mg][nt] = bv;
    }
    const ushort_t* wbase = wfrag + (wave*2*64 + lane)*8;
    f16x8 wf[2], af[4];
    #pragma unroll
    for (int nt = 0; nt < 2; ++nt) wf[nt] = *(const f16x8*)(wbase + nt*512);
    {
        const int o2 = (g*16) ^ swz;
        #pragma unroll
        for (int mg = 0; mg < 4; ++mg)
            af[mg] = *(const f16x8*)(smem + (mg*16 + l15)*ROWB + o2);
    }
    #pragma unroll
    for (int kc = 0; kc < KC; ++kc){
        f16x8 wfn[2], afn[4];
        if (kc + 1 < KC){
            const int off = (kc + 1)*64 + g*16;
            const int o2 = (off < 512) ? (off ^ swz) : (512 + ((off - 512) ^ swz2));
            #pragma unroll
            for (int mg = 0; mg < 4; ++mg)
                afn[mg] = *(const f16x8*)(smem + (mg*16 + l15)*ROWB + o2);
            const ushort_t* wp = wbase + (kc + 1)*8192;
            #pragma unroll
            for (int nt = 0; nt < 2; ++nt) wfn[nt] = *(const f16x8*)(wp + nt*512);
        }
        #pragma unroll
        for (int mg = 0; mg < 4; ++mg)
            #pragma unroll
            for (int nt = 0; nt < 2; ++nt)
                acc[mg][nt] = __builtin_amdgcn_mfma_f32_16x16x32_f16(wf[nt], af[mg], acc[mg][nt], 0, 0, 0);
        if (kc + 1 < KC){
            #pragma unroll
            for (int mg = 0; mg < 4; ++mg) af[mg] = afn[mg];
            wf[0] = wfn[0]; wf[1] = wfn[1];
        }
    }
    __syncthreads();   // all reads of current acts done before overwrite
    #pragma unroll
    for (int mg = 0; mg < 4; ++mg){
        char* row = smem + (mg*16 + l15)*ROWB;
        #pragma unroll
        for (int nt = 0; nt < 2; ++nt){
            const int NT = wave*2 + nt;
            f32x4 a = acc[mg][nt];
            unsigned long long w =
                  (unsigned long long)f2h(fmaxf(a[0], 0.f))
                | ((unsigned long long)f2h(fmaxf(a[1], 0.f)) << 16)
                | ((unsigned long long)f2h(fmaxf(a[2], 0.f)) << 32)
                | ((unsigned long long)f2h(fmaxf(a[3], 0.f)) << 48);
            const int off = (((NT >> 1)*64 + 16*g + 8*(NT & 1)) ^ swz);
            *(unsigned long long*)(row + off) = w;
        }
    }
    __syncthreads();
}

// ---------------- main fused kernel: gather + 4 MFMA layers + out layer ----------------
__global__ __launch_bounds__(512, 4) void liif_k(
        const float* __restrict__ coord, const float* __restrict__ cell,
        const float* __restrict__ b_in, const float* __restrict__ b_hid,
        const float* __restrict__ w_out, const float* __restrict__ b_out,
        const ushort_t* __restrict__ feat, const ushort_t* __restrict__ packW,
        float2* __restrict__ preds, float* __restrict__ areas)
{
    __shared__ __align__(16) char smem[64*ROWB];   // 36864 B
    const int t = threadIdx.x, lane = t & 63, wave = t >> 6;   // wave in [0,8)
    const int bi = blockIdx.x, v = bi & 3;
    const int tile = bi >> 2;
    const int b = tile >> 10, th = (tile >> 5) & 31, tw = tile & 31;

    // --- setup: gather feature rows + extras + area (8 threads per row, 64B each) ---
    {
        int m = t >> 3, q = t & 7;
        int qh = th*8 + (m >> 3), qw = tw*8 + (m & 7);
        int cidx = (((b<<8) + qh)<<8) + qw;
        float c0 = coord[cidx*2], c1 = coord[cidx*2 + 1];
        float ch = c0 + ((v & 2) ? 0.015625f : -0.015625f); ch = ch + 1e-6f;
        ch = fminf(fmaxf(ch, -1.f + 1e-6f), 1.f - 1e-6f);
        float cw = c1 + ((v & 1) ? 0.015625f : -0.015625f); cw = cw + 1e-6f;
        cw = fminf(fmaxf(cw, -1.f + 1e-6f), 1.f - 1e-6f);
        int ih = (int)floorf((ch + 1.f)*64.f*0.5f); ih = ih < 0 ? 0 : (ih > 63 ? 63 : ih);
        int iw = (int)floorf((cw + 1.f)*64.f*0.5f); iw = iw < 0 ? 0 : (iw > 63 ? 63 : iw);
        char* drow = smem + m*ROWB;
        int sw = (m & 7) << 4;
        const u64x2* src = (const u64x2*)(feat + ((((b<<6) + ih)<<6) + iw)*256 + q*32);
        #pragma unroll
        for (int c = 0; c < 4; ++c)
            *(u64x2*)(drow + ((q*64 + c*16) ^ sw)) = src[c];
        if (q == 0){
            float qch = (2.f*(float)ih + 1.f)*(1.f/64.f) - 1.f;
            float qcw = (2.f*(float)iw + 1.f)*(1.f/64.f) - 1.f;
            float relh = (c0 - qch)*64.f, relw = (c1 - qcw)*64.f;
            float rch = cell[b*2]*64.f, rcw = cell[b*2 + 1]*64.f;
            unsigned long long ex = (unsigned long long)f2h(relh)
                | ((unsigned long long)f2h(relw) << 16)
                | ((unsigned long long)f2h(rch)  << 32)
                | ((unsigned long long)f2h(rcw)  << 48);
            u64x2 e; e[0] = ex; e[1] = 0;
            u64x2 z; z[0] = 0;  z[1] = 0;
            // extras region [512,576): reduced swizzle (bits 4-5) to spread kc=8 reads
            int sw2 = (m & 3) << 4;
            #pragma unroll
            for (int c = 1; c < 4; ++c)
                *(u64x2*)(drow + 512 + ((c*16) ^ sw2)) = z;
            *(u64x2*)(drow + 512 + sw2) = e;
            areas[((v*2 + b)<<16) + (qh<<8) + qw] = fabsf(relh*relw) + 1e-9f;
        }
    }
    __syncthreads();

    // --- 4 MFMA layers (transposed) ---
    mlp_layer<9>(packW,                  b_in,        smem, lane, wave);
    mlp_layer<8>(packW + 73728,          b_hid,       smem, lane, wave);
    mlp_layer<8>(packW + 73728 + 65536,  b_hid + 256, smem, lane, wave);
    mlp_layer<8>(packW + 73728 + 131072, b_hid + 512, smem, lane, wave);

    // --- out layer 256->2 (fp32 VALU, 8 threads per row, 64 channels each) ---
    {
        int m = t >> 3, q = t & 7;
        char* drow = smem + m*ROWB;
        int sw = (m & 7) << 4;
        const float2* wo = (const float2*)w_out;
        float s0 = 0.f, s1 = 0.f;
        #pragma unroll
        for (int c = 0; c < 4; ++c){
            int o = q*64 + c*16;
            u64x2 chk = *(const u64x2*)(drow + (o ^ sw));
            int kblock = o >> 6, gg = (o >> 4) & 3;
            #pragma unroll
            for (int half = 0; half < 2; ++half){
                unsigned long long u = chk[half];
                #pragma unroll
                for (int jj = 0; jj < 4; ++jj){
                    int je = half*4 + jj;
                    int k = kblock*32 + 4*gg + (je & 3) + ((je >> 2) << 4);
                    float a = h2f((ushort_t)(u >> (16*jj)));
                    float2 wv = wo[k];
                    s0 += a*wv.x; s1 += a*wv.y;
                }
            }
        }
        s0 += __shfl_xor(s0, 1); s0 += __shfl_xor(s0, 2); s0 += __shfl_xor(s0, 4);
        s1 += __shfl_xor(s1, 1); s1 += __shfl_xor(s1, 2); s1 += __shfl_xor(s1, 4);
        if (q == 0){
            int qh = th*8 + (m >> 3), qw = tw*8 + (m & 7);
            float2 pr; pr.x = s0 + b_out[0]; pr.y = s1 + b_out[1];
            preds[((v*2 + b)<<16) + (qh<<8) + qw] = pr;
        }
    }
}

// ---------------- ensemble combine + softmax ----------------
__global__ __launch_bounds__(256) void comb_k(const float2* __restrict__ preds,
        const float* __restrict__ areas, float* __restrict__ out)
{
    int idx = blockIdx.x*256 + threadIdx.x;   // 131072
    int b = idx >> 16, pix = idx & 65535;
    float a[4]; float2 p[4];
    #pragma unroll
    for (int v = 0; v < 4; ++v){
        int base = ((v*2 + b)<<16) + pix;
        a[v] = areas[base]; p[v] = preds[base];
    }
    float tot = a[0] + a[1] + a[2] + a[3];
    float w0 = a[3]/tot, w1 = a[2]/tot, w2 = a[1]/tot, w3 = a[0]/tot;
    float r0 = p[0].x*w0 + p[1].x*w1 + p[2].x*w2 + p[3].x*w3;
    float r1 = p[0].y*w0 + p[1].y*w1 + p[2].y*w2 + p[3].y*w3;
    float mx = fmaxf(r0, r1);
    float e0 = expf(r0 - mx), e1 = expf(r1 - mx);
    float inv = 1.f/(e0 + e1);
    out[(b<<17) + pix]         = e0*inv;
    out[(b<<17) + 65536 + pix] = e1*inv;
}

extern "C" void kernel_launch(void* const* d_in, const int* in_sizes, int n_in,
                              void* d_out, int out_size, void* d_ws, size_t ws_size,
                              hipStream_t stream)
{
    const float* inp   = (const float*)d_in[0];
    const float* coord = (const float*)d_in[1];
    const float* cell  = (const float*)d_in[2];
    const float* convw = (const float*)d_in[3];
    const float* convb = (const float*)d_in[4];
    const float* w_in  = (const float*)d_in[5];
    const float* b_in  = (const float*)d_in[6];
    const float* w_hid = (const float*)d_in[7];
    const float* b_hid = (const float*)d_in[8];
    const float* w_out = (const float*)d_in[9];
    const float* b_out = (const float*)d_in[10];
    (void)in_sizes; (void)n_in; (void)out_size; (void)ws_size;

    char* ws = (char*)d_ws;
    ushort_t* feat  = (ushort_t*)ws;                                  // 4,194,304 B
    ushort_t* packW = (ushort_t*)(ws + 4194304);                      //   540,672 B
    float2*   preds = (float2*)(ws + 4194304 + 540672);               // 4,194,304 B
    float*    areas = (float*)(ws + 4194304 + 540672 + 4194304);      // 2,097,152 B
    float* out = (float*)d_out;

    pack_k<<<dim3(1056), dim3(256), 0, stream>>>(w_in, w_hid, packW);
    conv_k<<<dim3(8192), dim3(256), 0, stream>>>(inp, convw, convb, feat);
    liif_k<<<dim3(8192), dim3(512), 0, stream>>>(coord, cell, b_in, b_hid,
                                                 w_out, b_out, feat, packW, preds, areas);
    comb_k<<<dim3(512), dim3(256), 0, stream>>>(preds, areas, out);
}

// Round 9
// 401.132 us; speedup vs baseline: 1.9527x; 1.0578x over previous
//
#include <hip/hip_runtime.h>

typedef unsigned short ushort_t;
typedef __attribute__((ext_vector_type(8))) _Float16 f16x8;
typedef __attribute__((ext_vector_type(4))) float f32x4;
typedef __attribute__((ext_vector_type(4))) unsigned int u32x4;
typedef __attribute__((ext_vector_type(2))) unsigned long long u64x2;

#define ROWB 576   // 288 cols fp16 = 576B; swizzle XOR bits 4-6 in [0,512), bits 4-5 in [512,576)

__device__ __forceinline__ ushort_t f2h(float x){ _Float16 h=(_Float16)x; return __builtin_bit_cast(ushort_t,h); }
__device__ __forceinline__ float h2f(ushort_t u){ return (float)__builtin_bit_cast(_Float16,u); }
__device__ __forceinline__ unsigned int pkrtz(float lo, float hi){
    return __builtin_bit_cast(unsigned int, __builtin_amdgcn_cvt_pkrtz(lo, hi));
}

// physical position of logical channel c within its 32-channel block:
// slot group g = (c%16)/4 holds logical k = {4g..4g+3, 16+4g..16+4g+3} contiguously (16B)
__device__ __forceinline__ int permc(int c){
    return (c & ~31) + (((c >> 2) & 3) << 3) + (c & 3) + (((c >> 4) & 1) << 2);
}

// ---------------- conv 3x3, 3->256, SAME ----------------
__global__ __launch_bounds__(256) void conv_k(const float* __restrict__ inp,
        const float* __restrict__ w, const float* __restrict__ bias,
        ushort_t* __restrict__ feat)
{
    __shared__ float sw_[6912];
    __shared__ float patch[27];
    int t = threadIdx.x;
    int b = blockIdx.x >> 12, p = blockIdx.x & 4095;
    int y = p >> 6, x = p & 63;
    for (int i = t; i < 6912; i += 256) sw_[i] = w[i];
    if (t < 27){
        int ci = t/9, r = t%9, dy = r/3, dx = r%3;
        int yy = y+dy-1, xx = x+dx-1;
        patch[t] = (yy>=0 && yy<64 && xx>=0 && xx<64) ? inp[((b*3+ci)<<12)+(yy<<6)+xx] : 0.f;
    }
    __syncthreads();
    float acc = bias[t];
    #pragma unroll
    for (int j = 0; j < 27; ++j) acc += patch[j]*sw_[t*27+j];
    feat[(((b<<12)+p)<<8) + permc(t)] = f2h(acc);
}

// ---------------- pack weights into MFMA fragment order (fp16) ----------------
// layout: [layer][kc][ntile(16)][lane(64)][8], layer0: kc 0..8 (k 256..259 = extra dims, rest 0)
__global__ __launch_bounds__(256) void pack_k(const float* __restrict__ w_in,
        const float* __restrict__ w_hid, ushort_t* __restrict__ packW)
{
    int i = blockIdx.x*256 + threadIdx.x;
    if (i >= 270336) return;
    int layer, rem;
    if (i < 73728){ layer = 0; rem = i; }
    else { int j = i - 73728; layer = 1 + (j >> 16); rem = j & 65535; }
    int j8 = rem & 7, frag = rem >> 3;
    int lane = frag & 63, kt = frag >> 6;
    int kc = kt >> 4, nt = kt & 15;
    int k = kc*32 + ((lane>>4)<<2) + (j8 & 3) + ((j8 >> 2) << 4);
    int n = (nt<<4) + (lane & 15);
    float val;
    if (layer == 0) val = (k < 260) ? w_in[k*256 + n] : 0.f;
    else            val = w_hid[((layer-1)*256 + k)*256 + n];
    packW[i] = f2h(val);
}

// ---------------- fused MLP layer, TRANSPOSED: Y^T = W^T (A) * X^T (B) ----------------
// 4 waves; wave owns 64 output channels (tiles 4w..4w+3) for all 64 pixels.
// Per kc: 4 B-act ds_reads + 4 A-weight loads -> 16 MFMAs; both depth-1 prefetched.
// Store: tile pair (4w+2i, 4w+2i+1) = k-block 2w+i -> ONE b128 per (mg,i) via cvt_pkrtz.
template<int KC>
__device__ __forceinline__ void mlp_layer(const ushort_t* __restrict__ wfrag,
        const float* __restrict__ bias, char* smem, int lane, int wave)
{
    const int l15 = lane & 15, g = lane >> 4;
    const int swz  = (l15 & 7) << 4;
    const int swz2 = (l15 & 3) << 4;
    f32x4 acc[4][4];   // [mg][nt4]
    #pragma unroll
    for (int nt = 0; nt < 4; ++nt){
        f32x4 bv = *(const f32x4*)(bias + (wave*4 + nt)*16 + 4*g);
        #pragma unroll
        for (int mg = 0; mg < 4; ++mg) acc[mg][nt] = bv;
    }
    const ushort_t* wbase = wfrag + (wave*4*64 + lane)*8;
    f16x8 wf[4], af[4];
    #pragma unroll
    for (int nt = 0; nt < 4; ++nt) wf[nt] = *(const f16x8*)(wbase + nt*512);
    {
        const int o2 = (g*16) ^ swz;
        #pragma unroll
        for (int mg = 0; mg < 4; ++mg)
            af[mg] = *(const f16x8*)(smem + (mg*16 + l15)*ROWB + o2);
    }
    #pragma unroll
    for (int kc = 0; kc < KC; ++kc){
        f16x8 wfn[4], afn[4];
        if (kc + 1 < KC){
            const int off = (kc + 1)*64 + g*16;
            const int o2 = (off < 512) ? (off ^ swz) : (512 + ((off - 512) ^ swz2));
            #pragma unroll
            for (int mg = 0; mg < 4; ++mg)
                afn[mg] = *(const f16x8*)(smem + (mg*16 + l15)*ROWB + o2);
            const ushort_t* wp = wbase + (kc + 1)*8192;
            #pragma unroll
            for (int nt = 0; nt < 4; ++nt) wfn[nt] = *(const f16x8*)(wp + nt*512);
        }
        #pragma unroll
        for (int mg = 0; mg < 4; ++mg)
            #pragma unroll
            for (int nt = 0; nt < 4; ++nt)
                acc[mg][nt] = __builtin_amdgcn_mfma_f32_16x16x32_f16(wf[nt], af[mg], acc[mg][nt], 0, 0, 0);
        if (kc + 1 < KC){
            #pragma unroll
            for (int mg = 0; mg < 4; ++mg) af[mg] = afn[mg];
            #pragma unroll
            for (int nt = 0; nt < 4; ++nt) wf[nt] = wfn[nt];
        }
    }
    __syncthreads();   // all reads of current acts done before overwrite
    #pragma unroll
    for (int mg = 0; mg < 4; ++mg){
        char* row = smem + (mg*16 + l15)*ROWB;
        #pragma unroll
        for (int i = 0; i < 2; ++i){
            const int kb = 2*wave + i;
            f32x4 a0 = acc[mg][2*i], a1 = acc[mg][2*i + 1];
            u32x4 st;
            st[0] = pkrtz(fmaxf(a0[0],0.f), fmaxf(a0[1],0.f));
            st[1] = pkrtz(fmaxf(a0[2],0.f), fmaxf(a0[3],0.f));
            st[2] = pkrtz(fmaxf(a1[0],0.f), fmaxf(a1[1],0.f));
            st[3] = pkrtz(fmaxf(a1[2],0.f), fmaxf(a1[3],0.f));
            *(u32x4*)(row + ((kb*64 + 16*g) ^ swz)) = st;
        }
    }
    __syncthreads();
}

// ---------------- main fused kernel: gather + 4 MFMA layers + out layer ----------------
__global__ __launch_bounds__(256, 3) void liif_k(
        const float* __restrict__ coord, const float* __restrict__ cell,
        const float* __restrict__ b_in, const float* __restrict__ b_hid,
        const float* __restrict__ w_out, const float* __restrict__ b_out,
        const ushort_t* __restrict__ feat, const ushort_t* __restrict__ packW,
        float2* __restrict__ preds, float* __restrict__ areas)
{
    __shared__ __align__(16) char smem[64*ROWB];   // 36864 B
    const int t = threadIdx.x, lane = t & 63, wave = t >> 6;   // wave in [0,4)
    const int bi = blockIdx.x, v = bi & 3;
    const int tile = bi >> 2;
    const int b = tile >> 10, th = (tile >> 5) & 31, tw = tile & 31;

    // --- setup: gather feature rows + extras + area (4 threads per row, 128B each) ---
    {
        int m = t >> 2, q = t & 3;
        int qh = th*8 + (m >> 3), qw = tw*8 + (m & 7);
        int cidx = (((b<<8) + qh)<<8) + qw;
        float c0 = coord[cidx*2], c1 = coord[cidx*2 + 1];
        float ch = c0 + ((v & 2) ? 0.015625f : -0.015625f); ch = ch + 1e-6f;
        ch = fminf(fmaxf(ch, -1.f + 1e-6f), 1.f - 1e-6f);
        float cw = c1 + ((v & 1) ? 0.015625f : -0.015625f); cw = cw + 1e-6f;
        cw = fminf(fmaxf(cw, -1.f + 1e-6f), 1.f - 1e-6f);
        int ih = (int)floorf((ch + 1.f)*64.f*0.5f); ih = ih < 0 ? 0 : (ih > 63 ? 63 : ih);
        int iw = (int)floorf((cw + 1.f)*64.f*0.5f); iw = iw < 0 ? 0 : (iw > 63 ? 63 : iw);
        char* drow = smem + m*ROWB;
        int sw = (m & 7) << 4;
        const u64x2* src = (const u64x2*)(feat + ((((b<<6) + ih)<<6) + iw)*256 + q*64);
        #pragma unroll
        for (int c = 0; c < 8; ++c)
            *(u64x2*)(drow + ((q*128 + c*16) ^ sw)) = src[c];
        if (q == 0){
            float qch = (2.f*(float)ih + 1.f)*(1.f/64.f) - 1.f;
            float qcw = (2.f*(float)iw + 1.f)*(1.f/64.f) - 1.f;
            float relh = (c0 - qch)*64.f, relw = (c1 - qcw)*64.f;
            float rch = cell[b*2]*64.f, rcw = cell[b*2 + 1]*64.f;
            unsigned long long ex = (unsigned long long)f2h(relh)
                | ((unsigned long long)f2h(relw) << 16)
                | ((unsigned long long)f2h(rch)  << 32)
                | ((unsigned long long)f2h(rcw)  << 48);
            u64x2 e; e[0] = ex; e[1] = 0;
            u64x2 z; z[0] = 0;  z[1] = 0;
            // extras region [512,576): reduced swizzle (bits 4-5) to spread kc=8 reads
            int sw2 = (m & 3) << 4;
            #pragma unroll
            for (int c = 1; c < 4; ++c)
                *(u64x2*)(drow + 512 + ((c*16) ^ sw2)) = z;
            *(u64x2*)(drow + 512 + sw2) = e;
            areas[((v*2 + b)<<16) + (qh<<8) + qw] = fabsf(relh*relw) + 1e-9f;
        }
    }
    __syncthreads();

    // --- 4 MFMA layers (transposed, 4 waves x 4 ntiles) ---
    mlp_layer<9>(packW,                  b_in,        smem, lane, wave);
    mlp_layer<8>(packW + 73728,          b_hid,       smem, lane, wave);
    mlp_layer<8>(packW + 73728 + 65536,  b_hid + 256, smem, lane, wave);
    mlp_layer<8>(packW + 73728 + 131072, b_hid + 512, smem, lane, wave);

    // --- out layer 256->2 (fp32 VALU, 4 threads per row, 128 channels each) ---
    {
        int m = t >> 2, q = t & 3;
        char* drow = smem + m*ROWB;
        int sw = (m & 7) << 4;
        const float2* wo = (const float2*)w_out;
        float s0 = 0.f, s1 = 0.f;
        #pragma unroll
        for (int c = 0; c < 8; ++c){
            int o = q*128 + c*16;
            u64x2 chk = *(const u64x2*)(drow + (o ^ sw));
            int kblock = o >> 6, gg = (o >> 4) & 3;
            #pragma unroll
            for (int half = 0; half < 2; ++half){
                unsigned long long u = chk[half];
                #pragma unroll
                for (int jj = 0; jj < 4; ++jj){
                    int je = half*4 + jj;
                    int k = kblock*32 + 4*gg + (je & 3) + ((je >> 2) << 4);
                    float a = h2f((ushort_t)(u >> (16*jj)));
                    float2 wv = wo[k];
                    s0 += a*wv.x; s1 += a*wv.y;
                }
            }
        }
        s0 += __shfl_xor(s0, 1); s0 += __shfl_xor(s0, 2);
        s1 += __shfl_xor(s1, 1); s1 += __shfl_xor(s1, 2);
        if (q == 0){
            int qh = th*8 + (m >> 3), qw = tw*8 + (m & 7);
            float2 pr; pr.x = s0 + b_out[0]; pr.y = s1 + b_out[1];
            preds[((v*2 + b)<<16) + (qh<<8) + qw] = pr;
        }
    }
}

// ---------------- ensemble combine + softmax ----------------
__global__ __launch_bounds__(256) void comb_k(const float2* __restrict__ preds,
        const float* __restrict__ areas, float* __restrict__ out)
{
    int idx = blockIdx.x*256 + threadIdx.x;   // 131072
    int b = idx >> 16, pix = idx & 65535;
    float a[4]; float2 p[4];
    #pragma unroll
    for (int v = 0; v < 4; ++v){
        int base = ((v*2 + b)<<16) + pix;
        a[v] = areas[base]; p[v] = preds[base];
    }
    float tot = a[0] + a[1] + a[2] + a[3];
    float w0 = a[3]/tot, w1 = a[2]/tot, w2 = a[1]/tot, w3 = a[0]/tot;
    float r0 = p[0].x*w0 + p[1].x*w1 + p[2].x*w2 + p[3].x*w3;
    float r1 = p[0].y*w0 + p[1].y*w1 + p[2].y*w2 + p[3].y*w3;
    float mx = fmaxf(r0, r1);
    float e0 = expf(r0 - mx), e1 = expf(r1 - mx);
    float inv = 1.f/(e0 + e1);
    out[(b<<17) + pix]         = e0*inv;
    out[(b<<17) + 65536 + pix] = e1*inv;
}

extern "C" void kernel_launch(void* const* d_in, const int* in_sizes, int n_in,
                              void* d_out, int out_size, void* d_ws, size_t ws_size,
                              hipStream_t stream)
{
    const float* inp   = (const float*)d_in[0];
    const float* coord = (const float*)d_in[1];
    const float* cell  = (const float*)d_in[2];
    const float* convw = (const float*)d_in[3];
    const float* convb = (const float*)d_in[4];
    const float* w_in  = (const float*)d_in[5];
    const float* b_in  = (const float*)d_in[6];
    const float* w_hid = (const float*)d_in[7];
    const float* b_hid = (const float*)d_in[8];
    const float* w_out = (const float*)d_in[9];
    const float* b_out = (const float*)d_in[10];
    (void)in_sizes; (void)n_in; (void)out_size; (void)ws_size;

    char* ws = (char*)d_ws;
    ushort_t* feat  = (ushort_t*)ws;                                  // 4,194,304 B
    ushort_t* packW = (ushort_t*)(ws + 4194304);                      //   540,672 B
    float2*   preds = (float2*)(ws + 4194304 + 540672);               // 4,194,304 B
    float*    areas = (float*)(ws + 4194304 + 540672 + 4194304);      // 2,097,152 B
    float* out = (float*)d_out;

    pack_k<<<dim3(1056), dim3(256), 0, stream>>>(w_in, w_hid, packW);
    conv_k<<<dim3(8192), dim3(256), 0, stream>>>(inp, convw, convb, feat);
    liif_k<<<dim3(8192), dim3(256), 0, stream>>>(coord, cell, b_in, b_hid,
                                                 w_out, b_out, feat, packW, preds, areas);
    comb_k<<<dim3(512), dim3(256), 0, stream>>>(preds, areas, out);
}